// Round 11
// baseline (226.409 us; speedup 1.0000x reference)
//
#include <hip/hip_runtime.h>
#include <hip/hip_bf16.h>

// Shapes (fixed by the reference):
// lfi:    [B, U, H, W, C] f32   B=4, U=81, H=64, W=64, C=4
// f_maps: [B, H, W, F]    f32   F=32
// out:    [B, U, H, W, F] f32
#define BB 4
#define UU 81
#define HH 64
#define WW 64
#define CC 4
#define FF 32

typedef float fx4 __attribute__((ext_vector_type(4)));

// ws layout (floats): [0, 32768)     = partial[b][hs][slot]  (4*4*2048)
//                     [32768, 40960) = mask[b][y][f]         (4*2048)
#define WS_PARTIAL 0
#define WS_MASK 32768

// ---------------------------------------------------------------------------
// Kernel A1: partial h-sums. grid = (4 h-slices, 4 b), 1024 threads.
// ---------------------------------------------------------------------------
__global__ __launch_bounds__(1024) void mask_partial_kernel(
    const float* __restrict__ fmaps, float* __restrict__ ws) {
    const int hs = blockIdx.x;                 // 0..3
    const int b = blockIdx.y;
    const int t = threadIdx.x;                 // 0..1023
    const float* fb = fmaps + (size_t)b * HH * WW * FF + (size_t)hs * 16 * WW * FF;
    float* part = ws + WS_PARTIAL + ((size_t)b * 4 + hs) * (WW * FF);

#pragma unroll
    for (int r = 0; r < 2; ++r) {
        const int idx = t + r * 1024;          // slot = w*F + f
        float s = 0.f;
#pragma unroll
        for (int h = 0; h < 16; ++h) s += fb[h * WW * FF + idx];
        part[idx] = s;
    }
}

// ---------------------------------------------------------------------------
// Kernel A2: hv = sum of 4 partials (L2-hot), tree-max over w per (b,f),
// write normalized mask. grid = 4 (b), 256 threads, 8 slots/thread.
// ---------------------------------------------------------------------------
__global__ __launch_bounds__(256) void mask_norm_kernel(
    const float* __restrict__ ws_in, float* __restrict__ mask) {
    const int b = blockIdx.x;
    const int t = threadIdx.x;                 // 0..255
    __shared__ float sm[WW * FF];              // 2048 floats
    const float* part = ws_in + WS_PARTIAL + (size_t)b * 4 * (WW * FF);

    float v[8];
#pragma unroll
    for (int j = 0; j < 8; ++j) {
        const int i = t + 256 * j;
        float s = part[i] + part[WW * FF + i] + part[2 * WW * FF + i] +
                  part[3 * WW * FF + i];
        v[j] = s * (1.f / HH);
        sm[i] = v[j];
    }
    __syncthreads();

    // tree max over w: sm[w*32+f] <- max(sm[w*32+f], sm[(w+s)*32+f])
    for (int s = WW / 2; s > 0; s >>= 1) {
#pragma unroll
        for (int j = 0; j < 8; ++j) {
            const int i = t + 256 * j;
            const int w = i >> 5;
            if (w < s) sm[i] = fmaxf(sm[i], sm[i + s * FF]);
        }
        __syncthreads();
    }
    // sm[0..31] now holds per-f max over w
#pragma unroll
    for (int j = 0; j < 8; ++j) {
        const int i = t + 256 * j;
        mask[(size_t)b * WW * FF + i] = v[j] / sm[i & (FF - 1)];
    }
}

// ---------------------------------------------------------------------------
// Kernel B: out[b,u,y,x,f] = mean_c(lfi[b,u,y,x,:]) * mask[b,y,f]
// Identical to round 10. THIS ROUND'S EXPERIMENT IS IN kernel_launch:
// out_kernel is launched TWICE (idempotent; second launch stores identical
// values) so that T_out = dur_us(new) - dur_us(round10) measures the
// kernel's true duration, which the top-5 profile window cannot show.
// ---------------------------------------------------------------------------
#define NPT 8
__global__ __launch_bounds__(256) void out_kernel(
    const fx4* __restrict__ lfi4,   // [B*U*H*W] fx4 (C=4 contiguous)
    const fx4* __restrict__ mask4,  // [B*W*F/4] fx4
    fx4* __restrict__ out4) {       // [B*U*H*W*F/4]
    const int b = blockIdx.y;
    const fx4* __restrict__ lfiB  = lfi4  + (size_t)b * UU * HH * WW;
    const fx4* __restrict__ maskB = mask4 + (size_t)b * WW * (FF / 4);
    fx4* __restrict__ outB        = out4  + (size_t)b * UU * HH * WW * (FF / 4);

    const size_t base = (size_t)blockIdx.x * (256 * NPT) + threadIdx.x;
    const size_t r0 = base >> 3;               // lfi fx4 index for k=0
    const int f4 = (int)(base & 7);
    const int y0 = (int)((r0 >> 6) & 63);      // wave-uniform

    fx4 mk[NPT / 2];
#pragma unroll
    for (int j = 0; j < NPT / 2; ++j)
        mk[j] = maskB[((y0 + j) & 63) * 8 + f4];

    fx4 lf[NPT];
#pragma unroll
    for (int k = 0; k < NPT; ++k) lf[k] = lfiB[r0 + (size_t)k * 32];

#pragma unroll
    for (int k = 0; k < NPT; ++k) {
        const float m = (lf[k].x + lf[k].y + lf[k].z + lf[k].w) * 0.25f;
        outB[base + (size_t)k * 256] = m * mk[k >> 1];
    }
}

extern "C" void kernel_launch(void* const* d_in, const int* in_sizes, int n_in,
                              void* d_out, int out_size, void* d_ws, size_t ws_size,
                              hipStream_t stream) {
    const float* lfi = (const float*)d_in[0];
    const float* fmaps = (const float*)d_in[1];
    float* out = (float*)d_out;
    float* ws = (float*)d_ws;
    float* mask = ws + WS_MASK;

    mask_partial_kernel<<<dim3(4, BB), 1024, 0, stream>>>(fmaps, ws);
    mask_norm_kernel<<<BB, 256, 0, stream>>>(ws, mask);

    const size_t perB4 = (size_t)UU * HH * WW * (FF / 4);  // 2,654,208
    const int grid_x = (int)(perB4 / (256 * NPT));         // 1296 (exact)
    dim3 grid(grid_x, BB);
    // Launch TWICE: timing probe. Second launch writes identical values
    // (idempotent), so correctness and "same work every call" both hold.
    out_kernel<<<grid, 256, 0, stream>>>(
        (const fx4*)lfi, (const fx4*)mask, (fx4*)out);
    out_kernel<<<grid, 256, 0, stream>>>(
        (const fx4*)lfi, (const fx4*)mask, (fx4*)out);
}